// Round 13
// baseline (1024.367 us; speedup 1.0000x reference)
//
#include <hip/hip_runtime.h>
#include <math.h>

// GCN on MI355X. N=200000 nodes, E=6400000 edges.
// R13: src-bucket-ordered adjacency, built FREE inside k_build. R12 proved
// src-sorted neighbor lists buy ~95 us on the gathers (monotone per-thread
// sweep of p-space -> L2 holds the front), but its k_sortadj cost 397 us
// (1 block/CU, dependent LDS insertion chains). Now k_build scatters records
// in 25 src-bucket sweeps (src>>13; barrier between sweeps): each dst list
// comes out bucket-ordered by src at 8K-node granularity -- same locality
// mechanism, ~10 us instead of 397. k_sortadj deleted.
// Pipeline: LDS-binned counting-sort CSR + input-side aggregation (GCN
// linearity). MESSAGES STAY FP32 (bf16 fails 0.21 -- R7 bisect).

static constexpr int NN = 200000;
static constexpr int NE = 6400000;
static constexpr int BK = 256;

static constexpr int SUBW  = 512;                    // nodes per sub-bin (pow2)
static constexpr int NBA   = (NN + SUBW - 1) / SUBW; // 391 sub-bins
static constexpr int CAP   = 32;                     // LDS bin capacity (recs)
static constexpr int FLUSH = 16;                     // flush granule = 64B
static constexpr int CAPB  = 18400;                  // per-bin staging cap (+15.7 sigma), %16==0
static constexpr int BKP   = 512;                    // k_part block threads
static constexpr int EPT   = 4;                      // edges per thread per chunk
static constexpr int CHUNK = BKP * EPT;              // 2048 edges per chunk
static constexpr int GPART = 768;                    // 3 blocks/CU (LDS-limited)
static constexpr int SRCSH = 13;                     // src-bucket shift (8K nodes/bucket)
static constexpr int NSWP  = (NN + (1 << SRCSH) - 1) >> SRCSH;  // 25 sweeps

// ---------- pass 1: LDS-binned partition of edges into per-sub-bin staging ----------
__global__ void __launch_bounds__(BKP) k_part(const int* __restrict__ srcI,
                                              const int* __restrict__ dstI,
                                              unsigned* __restrict__ stg,
                                              int* __restrict__ gtail, int e) {
  __shared__ unsigned bin[CAP][NBA];   // [slot][bin]: random-bin writes spread banks
  __shared__ int bcnt[NBA];
  for (int t = threadIdx.x; t < NBA; t += BKP) bcnt[t] = 0;
  __syncthreads();
  int nchunks = (e + CHUNK - 1) / CHUNK;
  for (int c = blockIdx.x; c < nchunks; c += gridDim.x) {
    int base_i = c * CHUNK;
    int dv[EPT], sv[EPT];
#pragma unroll
    for (int u = 0; u < EPT; ++u) {
      int i = base_i + u * BKP + (int)threadIdx.x;
      dv[u] = (i < e) ? __builtin_nontemporal_load(dstI + i) : -1;
      sv[u] = (i < e) ? __builtin_nontemporal_load(srcI + i) : 0;
    }
#pragma unroll
    for (int u = 0; u < EPT; ++u) {
      if (dv[u] >= 0) {
        int b = dv[u] >> 9;
        unsigned rec = ((unsigned)(dv[u] & (SUBW - 1)) << 18) | (unsigned)sv[u];
        int p = atomicAdd(&bcnt[b], 1);
        if (p < CAP) {
          bin[p][b] = rec;
        } else {
          int base = atomicAdd(&gtail[b], 1);               // rare overflow fallback
          stg[(size_t)b * CAPB + base] = rec;
        }
      }
    }
    __syncthreads();
    int b2 = threadIdx.x;                                   // single-pass flush sweep
    if (b2 < NBA) {
      int c2 = bcnt[b2];
      if (c2 > CAP) c2 = CAP;
      if (c2 >= FLUSH) {
        int nfl = c2 & ~(FLUSH - 1);
        int base = atomicAdd(&gtail[b2], nfl);
        size_t o = (size_t)b2 * CAPB + base;
        for (int k = 0; k < nfl; k += 4) {
          uint4 v;
          v.x = bin[k][b2]; v.y = bin[k + 1][b2]; v.z = bin[k + 2][b2]; v.w = bin[k + 3][b2];
          *(uint4*)(stg + o + k) = v;                       // base%16==0 -> aligned
        }
        int r = c2 - nfl;
        for (int k = 0; k < r; ++k) bin[k][b2] = bin[nfl + k][b2];
        bcnt[b2] = r;
      }
    }
    __syncthreads();
  }
  int b2 = threadIdx.x;                                     // final residual flush
  if (b2 < NBA) {
    int c2 = bcnt[b2];
    if (c2 > CAP) c2 = CAP;
    if (c2 > 0) {
      int base = atomicAdd(&gtail[b2], c2);
      size_t o = (size_t)b2 * CAPB + base;
      for (int k = 0; k < c2; ++k) stg[o + k] = bin[k][b2];
    }
  }
}

// ---------- exclusive scan over sub-bin sizes (single block, 512 thr) ----------
__global__ void k_scan_sub(const int* __restrict__ gtail, int* __restrict__ sbase) {
  __shared__ int s0[512], s1[512];
  int t = threadIdx.x;
  int v = (t < NBA) ? gtail[t] : 0;
  s0[t] = v;
  __syncthreads();
  int* a = s0; int* b = s1;
  for (int off = 1; off < 512; off <<= 1) {
    int x = a[t] + ((t >= off) ? a[t - off] : 0);
    b[t] = x;
    __syncthreads();
    int* tmp = a; a = b; b = tmp;
  }
  if (t < NBA) sbase[t] = a[t] - v;  // exclusive
}

// ---------- pass 2: per-sub-bin hist + scan + src-bucket-ordered scatter ----------
__global__ void __launch_bounds__(BK) k_build(const unsigned* __restrict__ stg,
                                              const int* __restrict__ gtail,
                                              const int* __restrict__ sbase,
                                              int* __restrict__ rowptr,
                                              int* __restrict__ adj) {
  __shared__ int hist[SUBW];
  __shared__ int s0[SUBW], s1[SUBW];
  int b = blockIdx.x;
  int m = gtail[b]; if (m > CAPB) m = CAPB;
  size_t off = (size_t)b * CAPB;
  int base = sbase[b];
  if (b == NBA - 1 && threadIdx.x == 0) rowptr[NN] = base + m;  // dense total
  for (int t = threadIdx.x; t < SUBW; t += BK) hist[t] = 0;
  __syncthreads();
  for (int k = threadIdx.x; k < m; k += BK) atomicAdd(&hist[stg[off + k] >> 18], 1);
  __syncthreads();
  for (int t = threadIdx.x; t < SUBW; t += BK) s0[t] = hist[t];
  __syncthreads();
  int* a = s0; int* bb = s1;
  for (int o2 = 1; o2 < SUBW; o2 <<= 1) {
    for (int t = threadIdx.x; t < SUBW; t += BK) bb[t] = a[t] + ((t >= o2) ? a[t - o2] : 0);
    __syncthreads();
    int* tmp = a; a = bb; bb = tmp;
  }
  for (int t = threadIdx.x; t < SUBW; t += BK) {
    int node = b * SUBW + t;
    int ex = a[t] - hist[t];
    if (node < NN) rowptr[node] = base + ex;
    bb[t] = ex;  // cur init
  }
  __syncthreads();
  int* cur = bb;
  // src-bucket-ordered scatter: sweep w takes only records with src in
  // bucket w (stg slab is 64KB L2-resident; 25 re-reads ~ free). Barrier
  // between sweeps makes each dst list bucket-ordered by src -> gathers
  // walk p-space monotonically (R12's locality win without its 397us sort).
  for (int w = 0; w < NSWP; ++w) {
    for (int k = threadIdx.x; k < m; k += BK) {
      unsigned rec = stg[off + k];
      unsigned src = rec & 0x3FFFFu;
      if ((int)(src >> SRCSH) == w) {
        int dl = rec >> 18;
        int p = atomicAdd(&cur[dl], 1);
        adj[base + p] = (int)src;          // single-block 64KB region: L2-resident
      }
    }
    __syncthreads();
  }
}

__global__ void k_zero(int* __restrict__ p, int n) {
  int i = blockIdx.x * blockDim.x + threadIdx.x;
  if (i < n) p[i] = 0;
}

// counts = rowptr diff (dense packing from counting sort)
__global__ void k_dinv(const int* __restrict__ rowptr, float* __restrict__ dinv, int n) {
  int i = blockIdx.x * blockDim.x + threadIdx.x;
  if (i < n) dinv[i] = rsqrtf(1.0f + (float)(rowptr[i + 1] - rowptr[i]));
}

// p1[i] = dinv[i] * x[i]  (3 -> padded 4 words)
__global__ void k_prep(const float* __restrict__ x, const float* __restrict__ dinv,
                       float* __restrict__ p1, int n) {
  int i = blockIdx.x * blockDim.x + threadIdx.x;
  if (i >= n) return;
  float di = dinv[i];
  float4 v;
  v.x = di * x[3 * (size_t)i];
  v.y = di * x[3 * (size_t)i + 1];
  v.z = di * x[3 * (size_t)i + 2];
  v.w = 0.f;
  *(float4*)(p1 + 4 * (size_t)i) = v;
}

template <int PIN>
__device__ inline void row_add(const float* __restrict__ row, float* __restrict__ acc) {
#pragma unroll
  for (int j = 0; j < PIN; j += 4) {
    float4 v = *(const float4*)(row + j);  // PIN in {4,8,16}: rows never straddle need
    acc[j] += v.x; acc[j + 1] += v.y; acc[j + 2] += v.z; acc[j + 3] += v.w;
  }
}

// ---------- neighbor accumulation (src-bucket-sorted lists -> L2 sweep) ----------
template <int PIN>
__device__ inline void gather_acc(const int* __restrict__ adj, int st, int en,
                                  const float* __restrict__ pin, float* __restrict__ acc) {
  int k = st;
  for (; k + 4 <= en; k += 4) {
    int s0 = adj[k], s1 = adj[k + 1], s2 = adj[k + 2], s3 = adj[k + 3];
    row_add<PIN>(pin + (size_t)s0 * PIN, acc);
    row_add<PIN>(pin + (size_t)s1 * PIN, acc);
    row_add<PIN>(pin + (size_t)s2 * PIN, acc);
    row_add<PIN>(pin + (size_t)s3 * PIN, acc);
  }
  for (; k < en; ++k) row_add<PIN>(pin + (size_t)adj[k] * PIN, acc);
}

// ---------- fused gather: q = sum p[s]; h = dinv*(q@W)+b; act; p_out = dinv*act ----------
// MODE 0: tanh   MODE 1: l2norm then tanh
template <int PIN, int FIN, int FOUT, int POUT, int MODE>
__global__ void __launch_bounds__(BK) k_gather_fused(
    const int* __restrict__ adj, const int* __restrict__ rowptr,
    const float* __restrict__ pin, const float* __restrict__ W,
    const float* __restrict__ bias, const float* __restrict__ dinv,
    float* __restrict__ pout, int n) {
  __shared__ float sW[FIN * FOUT];
  __shared__ float sb[FOUT];
  for (int t = threadIdx.x; t < FIN * FOUT; t += BK) sW[t] = W[t];
  if (threadIdx.x < FOUT) sb[threadIdx.x] = bias[threadIdx.x];
  __syncthreads();
  int i = blockIdx.x * blockDim.x + threadIdx.x;
  if (i >= n) return;
  float acc[PIN] = {};
  row_add<PIN>(pin + (size_t)i * PIN, acc);  // self-loop
  gather_acc<PIN>(adj, rowptr[i], rowptr[i + 1], pin, acc);
  float di = dinv[i];
  float h[FOUT];
  float ss = 0.f;
#pragma unroll
  for (int j = 0; j < FOUT; ++j) {
    float s = 0.f;
#pragma unroll
    for (int kk = 0; kk < FIN; ++kk) s = fmaf(acc[kk], sW[kk * FOUT + j], s);
    float t = fmaf(di, s, sb[j]);
    h[j] = t;
    ss += t * t;
  }
  float o[POUT];
#pragma unroll
  for (int j = 0; j < POUT; ++j) o[j] = 0.f;
  if (MODE == 0) {
#pragma unroll
    for (int j = 0; j < FOUT; ++j) o[j] = di * tanhf(h[j]);
  } else {
    float inv = 1.f / fmaxf(sqrtf(ss), 1e-12f);
#pragma unroll
    for (int j = 0; j < FOUT; ++j) o[j] = di * tanhf(h[j] * inv);
  }
  float* po = pout + (size_t)i * POUT;
#pragma unroll
  for (int j = 0; j < POUT; j += 4) *(float4*)(po + j) = make_float4(o[j], o[j+1], o[j+2], o[j+3]);
}

// ---------- final: gather(F_in=12) -> W3 -> l2norm -> Wc -> l2norm -> out ----------
__global__ void __launch_bounds__(BK) k_gather_final(
    const int* __restrict__ adj, const int* __restrict__ rowptr,
    const float* __restrict__ pin, const float* __restrict__ W3,
    const float* __restrict__ b3, const float* __restrict__ Wc,
    const float* __restrict__ bc, const float* __restrict__ dinv,
    float* __restrict__ out, int n) {
  constexpr int PIN = 16, FIN = 12, FOUT = 24, FC = 13;
  __shared__ float sW[FIN * FOUT];
  __shared__ float sb[FOUT];
  __shared__ float sWc[FOUT * FC];
  __shared__ float sbc[FC];
  for (int t = threadIdx.x; t < FIN * FOUT; t += BK) sW[t] = W3[t];
  for (int t = threadIdx.x; t < FOUT * FC; t += BK) sWc[t] = Wc[t];
  if (threadIdx.x < FOUT) sb[threadIdx.x] = b3[threadIdx.x];
  if (threadIdx.x < FC) sbc[threadIdx.x] = bc[threadIdx.x];
  __syncthreads();
  int i = blockIdx.x * blockDim.x + threadIdx.x;
  if (i >= n) return;
  float acc[PIN] = {};
  row_add<PIN>(pin + (size_t)i * PIN, acc);
  gather_acc<PIN>(adj, rowptr[i], rowptr[i + 1], pin, acc);
  float di = dinv[i];
  float h[FOUT];
  float ss = 0.f;
#pragma unroll
  for (int j = 0; j < FOUT; ++j) {
    float s = 0.f;
#pragma unroll
    for (int kk = 0; kk < FIN; ++kk) s = fmaf(acc[kk], sW[kk * FOUT + j], s);
    float t = fmaf(di, s, sb[j]);
    h[j] = t;
    ss += t * t;
  }
  float inv = 1.f / fmaxf(sqrtf(ss), 1e-12f);   // act3 = l2norm(h)
  float v[FC];
  float ss2 = 0.f;
#pragma unroll
  for (int j = 0; j < FC; ++j) {
    float s = sbc[j];
#pragma unroll
    for (int kk = 0; kk < FOUT; ++kk) s = fmaf(h[kk] * inv, sWc[kk * FC + j], s);
    v[j] = s;
    ss2 += s * s;
  }
  float inv2 = 1.f / fmaxf(sqrtf(ss2), 1e-12f);
#pragma unroll
  for (int j = 0; j < FC; ++j) out[(size_t)i * FC + j] = v[j] * inv2;
}

extern "C" void kernel_launch(void* const* d_in, const int* in_sizes, int n_in,
                              void* d_out, int out_size, void* d_ws, size_t ws_size,
                              hipStream_t stream) {
  const float* x  = (const float*)d_in[0];
  const int*   ei = (const int*)d_in[1];
  const float* W1 = (const float*)d_in[2];
  const float* b1 = (const float*)d_in[3];
  const float* W2 = (const float*)d_in[4];
  const float* b2 = (const float*)d_in[5];
  const float* W3 = (const float*)d_in[6];
  const float* b3 = (const float*)d_in[7];
  const float* Wc = (const float*)d_in[8];
  const float* bc = (const float*)d_in[9];
  float* out = (float*)d_out;

  const int n = NN;
  const int e = NE;
  const int* srcI = ei;       // row 0
  const int* dstI = ei + e;   // row 1

  // Workspace (words):
  //   dinv[N] | rowptr[N+8] | gtail[512] | sbase[512] | adj[E] | pad->64B | R
  // R hosts stg[NBA*CAPB] during build, then p1[4N] | p2[8N] | p3[16N].
  // p1 is 64B-aligned; 4N*4B and 8N*4B are multiples of 64 -> p2,p3 aligned.
  // Total ~56.0 MB (R8 proved >= 76 MB safe).
  float* ws = (float*)d_ws;
  float* dinv  = ws;
  int* rowptr  = (int*)(ws + n);            // N+8 (uses N+1, padded)
  int* gtail   = rowptr + n + 8;
  int* sbase   = gtail + 512;
  int* adj     = sbase + 512;
  size_t roff = (size_t)n + (n + 8) + 512 + 512 + e;
  roff = (roff + 15) & ~(size_t)15;         // round to 16 words = 64B
  float* R     = ws + roff;
  unsigned* stg = (unsigned*)R;
  float* p1 = R;                            // 4N  (64B-aligned)
  float* p2 = R + (size_t)4 * n;            // 8N  (64B-aligned)
  float* p3 = R + (size_t)12 * n;           // 16N (64B-aligned)

  const int gn = (n + BK - 1) / BK;

  // --- CSR build via binned counting sort, src-bucket-ordered scatter ---
  k_zero<<<2, BK, 0, stream>>>(gtail, 512);
  k_part<<<GPART, BKP, 0, stream>>>(srcI, dstI, stg, gtail, e);
  k_scan_sub<<<1, 512, 0, stream>>>(gtail, sbase);
  k_build<<<NBA, BK, 0, stream>>>(stg, gtail, sbase, rowptr, adj);
  k_dinv<<<gn, BK, 0, stream>>>(rowptr, dinv, n);

  // --- p1 = dinv * x ---
  k_prep<<<gn, BK, 0, stream>>>(x, dinv, p1, n);

  // --- Layer 1: gather p1 (16B rows) -> W1 -> tanh -> p2 = dinv*act ---
  k_gather_fused<4, 3, 6, 8, 0><<<gn, BK, 0, stream>>>(adj, rowptr, p1, W1, b1, dinv, p2, n);

  // --- Layer 2: gather p2 (32B rows) -> W2 -> l2norm+tanh -> p3 = dinv*act ---
  k_gather_fused<8, 6, 12, 16, 1><<<gn, BK, 0, stream>>>(adj, rowptr, p2, W2, b2, dinv, p3, n);

  // --- Layer 3 + classifier: gather p3 (64B rows) -> W3 -> l2norm -> Wc -> l2norm ---
  k_gather_final<<<gn, BK, 0, stream>>>(adj, rowptr, p3, W3, b3, Wc, bc, dinv, out, n);
}

// Round 14
// 540.489 us; speedup vs baseline: 1.8953x; 1.8953x over previous
//
#include <hip/hip_runtime.h>
#include <math.h>

// GCN on MI355X. N=200000 nodes, E=6400000 edges.
// R14: exact src-bucket ordering in ONE k_build scatter pass via 2-D LDS
// histogram hist2[dlocal][src>>13] (512x25). R13's 25-sweep version re-read
// the stg slabs past L2 (FETCH 272 MB) and sparsely re-dirtied adj lines
// (WRITE 161 MB) -> 570 us. Here: stg read exactly twice (hist + scatter),
// adj written once; record lands at base + ex[dl] + off2d[dl][sb] + arrival.
// R12 proved src-ordered adjacency buys ~95 us on the gathers (monotone
// p-space sweep -> L2 holds the front); this gets that order for ~30 us.
// Pipeline: LDS-binned counting-sort CSR + input-side aggregation (GCN
// linearity). MESSAGES STAY FP32 (bf16 fails 0.21 -- R7 bisect).

static constexpr int NN = 200000;
static constexpr int NE = 6400000;
static constexpr int BK = 256;

static constexpr int SUBW  = 512;                    // nodes per sub-bin (pow2)
static constexpr int NBA   = (NN + SUBW - 1) / SUBW; // 391 sub-bins
static constexpr int CAP   = 32;                     // LDS bin capacity (recs)
static constexpr int FLUSH = 16;                     // flush granule = 64B
static constexpr int CAPB  = 18400;                  // per-bin staging cap (+15.7 sigma), %16==0
static constexpr int BKP   = 512;                    // k_part block threads
static constexpr int EPT   = 4;                      // edges per thread per chunk
static constexpr int CHUNK = BKP * EPT;              // 2048 edges per chunk
static constexpr int GPART = 768;                    // 3 blocks/CU (LDS-limited)
static constexpr int SRCSH = 13;                     // src-bucket shift (8K nodes = 512KB of p3)
static constexpr int NSB   = (NN + (1 << SRCSH) - 1) >> SRCSH;  // 25 buckets

// ---------- pass 1: LDS-binned partition of edges into per-sub-bin staging ----------
__global__ void __launch_bounds__(BKP) k_part(const int* __restrict__ srcI,
                                              const int* __restrict__ dstI,
                                              unsigned* __restrict__ stg,
                                              int* __restrict__ gtail, int e) {
  __shared__ unsigned bin[CAP][NBA];   // [slot][bin]: random-bin writes spread banks
  __shared__ int bcnt[NBA];
  for (int t = threadIdx.x; t < NBA; t += BKP) bcnt[t] = 0;
  __syncthreads();
  int nchunks = (e + CHUNK - 1) / CHUNK;
  for (int c = blockIdx.x; c < nchunks; c += gridDim.x) {
    int base_i = c * CHUNK;
    int dv[EPT], sv[EPT];
#pragma unroll
    for (int u = 0; u < EPT; ++u) {
      int i = base_i + u * BKP + (int)threadIdx.x;
      dv[u] = (i < e) ? __builtin_nontemporal_load(dstI + i) : -1;
      sv[u] = (i < e) ? __builtin_nontemporal_load(srcI + i) : 0;
    }
#pragma unroll
    for (int u = 0; u < EPT; ++u) {
      if (dv[u] >= 0) {
        int b = dv[u] >> 9;
        unsigned rec = ((unsigned)(dv[u] & (SUBW - 1)) << 18) | (unsigned)sv[u];
        int p = atomicAdd(&bcnt[b], 1);
        if (p < CAP) {
          bin[p][b] = rec;
        } else {
          int base = atomicAdd(&gtail[b], 1);               // rare overflow fallback
          stg[(size_t)b * CAPB + base] = rec;
        }
      }
    }
    __syncthreads();
    int b2 = threadIdx.x;                                   // single-pass flush sweep
    if (b2 < NBA) {
      int c2 = bcnt[b2];
      if (c2 > CAP) c2 = CAP;
      if (c2 >= FLUSH) {
        int nfl = c2 & ~(FLUSH - 1);
        int base = atomicAdd(&gtail[b2], nfl);
        size_t o = (size_t)b2 * CAPB + base;
        for (int k = 0; k < nfl; k += 4) {
          uint4 v;
          v.x = bin[k][b2]; v.y = bin[k + 1][b2]; v.z = bin[k + 2][b2]; v.w = bin[k + 3][b2];
          *(uint4*)(stg + o + k) = v;                       // base%16==0 -> aligned
        }
        int r = c2 - nfl;
        for (int k = 0; k < r; ++k) bin[k][b2] = bin[nfl + k][b2];
        bcnt[b2] = r;
      }
    }
    __syncthreads();
  }
  int b2 = threadIdx.x;                                     // final residual flush
  if (b2 < NBA) {
    int c2 = bcnt[b2];
    if (c2 > CAP) c2 = CAP;
    if (c2 > 0) {
      int base = atomicAdd(&gtail[b2], c2);
      size_t o = (size_t)b2 * CAPB + base;
      for (int k = 0; k < c2; ++k) stg[o + k] = bin[k][b2];
    }
  }
}

// ---------- exclusive scan over sub-bin sizes (single block, 512 thr) ----------
__global__ void k_scan_sub(const int* __restrict__ gtail, int* __restrict__ sbase) {
  __shared__ int s0[512], s1[512];
  int t = threadIdx.x;
  int v = (t < NBA) ? gtail[t] : 0;
  s0[t] = v;
  __syncthreads();
  int* a = s0; int* b = s1;
  for (int off = 1; off < 512; off <<= 1) {
    int x = a[t] + ((t >= off) ? a[t - off] : 0);
    b[t] = x;
    __syncthreads();
    int* tmp = a; a = b; b = tmp;
  }
  if (t < NBA) sbase[t] = a[t] - v;  // exclusive
}

// ---------- pass 2: 2-D hist + scans + ONE ordered scatter -> rowptr, adj ----------
__global__ void __launch_bounds__(BK) k_build(const unsigned* __restrict__ stg,
                                              const int* __restrict__ gtail,
                                              const int* __restrict__ sbase,
                                              int* __restrict__ rowptr,
                                              int* __restrict__ adj) {
  __shared__ unsigned hist2[SUBW * NSB];   // 51.2 KB: [dl][sb] counts -> offsets
  __shared__ int htot[SUBW];               // per-dl total
  __shared__ int s0[SUBW], s1[SUBW];
  int b = blockIdx.x;
  int m = gtail[b]; if (m > CAPB) m = CAPB;
  size_t off = (size_t)b * CAPB;
  int base = sbase[b];
  if (b == NBA - 1 && threadIdx.x == 0) rowptr[NN] = base + m;  // dense total
  for (int t = threadIdx.x; t < SUBW * NSB; t += BK) hist2[t] = 0;
  __syncthreads();
  // read 1: 2-D histogram
  for (int k = threadIdx.x; k < m; k += BK) {
    unsigned rec = stg[off + k];
    int dl = rec >> 18;
    int sb = (int)((rec & 0x3FFFFu) >> SRCSH);
    atomicAdd(&hist2[dl * NSB + sb], 1u);
  }
  __syncthreads();
  // per-dl serial exclusive scan over sb (dl stride 25 is odd -> banks spread)
  for (int dl = threadIdx.x; dl < SUBW; dl += BK) {
    unsigned run = 0;
    for (int sb = 0; sb < NSB; ++sb) {
      unsigned c = hist2[dl * NSB + sb];
      hist2[dl * NSB + sb] = run;
      run += c;
    }
    htot[dl] = (int)run;
    s0[dl] = (int)run;
  }
  __syncthreads();
  // block inclusive scan over 512 dls (ping-pong)
  int* a = s0; int* bb = s1;
  for (int o2 = 1; o2 < SUBW; o2 <<= 1) {
    for (int t = threadIdx.x; t < SUBW; t += BK) bb[t] = a[t] + ((t >= o2) ? a[t - o2] : 0);
    __syncthreads();
    int* tmp = a; a = bb; bb = tmp;
  }
  for (int t = threadIdx.x; t < SUBW; t += BK) {
    int node = b * SUBW + t;
    int ex = a[t] - htot[t];
    if (node < NN) rowptr[node] = base + ex;
    bb[t] = ex;  // dst-base offsets live in the free scan buffer
  }
  __syncthreads();
  // read 2: single ordered scatter. pos = ex[dl] + off2d[dl][sb] + arrival.
  // adj exactly grouped by dst, exactly src-bucket-ordered within dst.
  for (int k = threadIdx.x; k < m; k += BK) {
    unsigned rec = stg[off + k];
    int dl = rec >> 18;
    unsigned src = rec & 0x3FFFFu;
    int sb = (int)(src >> SRCSH);
    int p = bb[dl] + (int)atomicAdd(&hist2[dl * NSB + sb], 1u);
    adj[base + p] = (int)src;          // single-block 64KB region, written once
  }
}

__global__ void k_zero(int* __restrict__ p, int n) {
  int i = blockIdx.x * blockDim.x + threadIdx.x;
  if (i < n) p[i] = 0;
}

// counts = rowptr diff (dense packing from counting sort)
__global__ void k_dinv(const int* __restrict__ rowptr, float* __restrict__ dinv, int n) {
  int i = blockIdx.x * blockDim.x + threadIdx.x;
  if (i < n) dinv[i] = rsqrtf(1.0f + (float)(rowptr[i + 1] - rowptr[i]));
}

// p1[i] = dinv[i] * x[i]  (3 -> padded 4 words)
__global__ void k_prep(const float* __restrict__ x, const float* __restrict__ dinv,
                       float* __restrict__ p1, int n) {
  int i = blockIdx.x * blockDim.x + threadIdx.x;
  if (i >= n) return;
  float di = dinv[i];
  float4 v;
  v.x = di * x[3 * (size_t)i];
  v.y = di * x[3 * (size_t)i + 1];
  v.z = di * x[3 * (size_t)i + 2];
  v.w = 0.f;
  *(float4*)(p1 + 4 * (size_t)i) = v;
}

template <int PIN>
__device__ inline void row_add(const float* __restrict__ row, float* __restrict__ acc) {
#pragma unroll
  for (int j = 0; j < PIN; j += 4) {
    float4 v = *(const float4*)(row + j);  // PIN in {4,8,16}: 16B-aligned rows
    acc[j] += v.x; acc[j + 1] += v.y; acc[j + 2] += v.z; acc[j + 3] += v.w;
  }
}

// ---------- neighbor accumulation (src-bucket-ordered lists -> L2 sweep) ----------
template <int PIN>
__device__ inline void gather_acc(const int* __restrict__ adj, int st, int en,
                                  const float* __restrict__ pin, float* __restrict__ acc) {
  int k = st;
  for (; k + 4 <= en; k += 4) {
    int s0 = adj[k], s1 = adj[k + 1], s2 = adj[k + 2], s3 = adj[k + 3];
    row_add<PIN>(pin + (size_t)s0 * PIN, acc);
    row_add<PIN>(pin + (size_t)s1 * PIN, acc);
    row_add<PIN>(pin + (size_t)s2 * PIN, acc);
    row_add<PIN>(pin + (size_t)s3 * PIN, acc);
  }
  for (; k < en; ++k) row_add<PIN>(pin + (size_t)adj[k] * PIN, acc);
}

// ---------- fused gather: q = sum p[s]; h = dinv*(q@W)+b; act; p_out = dinv*act ----------
// MODE 0: tanh   MODE 1: l2norm then tanh
template <int PIN, int FIN, int FOUT, int POUT, int MODE>
__global__ void __launch_bounds__(BK) k_gather_fused(
    const int* __restrict__ adj, const int* __restrict__ rowptr,
    const float* __restrict__ pin, const float* __restrict__ W,
    const float* __restrict__ bias, const float* __restrict__ dinv,
    float* __restrict__ pout, int n) {
  __shared__ float sW[FIN * FOUT];
  __shared__ float sb[FOUT];
  for (int t = threadIdx.x; t < FIN * FOUT; t += BK) sW[t] = W[t];
  if (threadIdx.x < FOUT) sb[threadIdx.x] = bias[threadIdx.x];
  __syncthreads();
  int i = blockIdx.x * blockDim.x + threadIdx.x;
  if (i >= n) return;
  float acc[PIN] = {};
  row_add<PIN>(pin + (size_t)i * PIN, acc);  // self-loop
  gather_acc<PIN>(adj, rowptr[i], rowptr[i + 1], pin, acc);
  float di = dinv[i];
  float h[FOUT];
  float ss = 0.f;
#pragma unroll
  for (int j = 0; j < FOUT; ++j) {
    float s = 0.f;
#pragma unroll
    for (int kk = 0; kk < FIN; ++kk) s = fmaf(acc[kk], sW[kk * FOUT + j], s);
    float t = fmaf(di, s, sb[j]);
    h[j] = t;
    ss += t * t;
  }
  float o[POUT];
#pragma unroll
  for (int j = 0; j < POUT; ++j) o[j] = 0.f;
  if (MODE == 0) {
#pragma unroll
    for (int j = 0; j < FOUT; ++j) o[j] = di * tanhf(h[j]);
  } else {
    float inv = 1.f / fmaxf(sqrtf(ss), 1e-12f);
#pragma unroll
    for (int j = 0; j < FOUT; ++j) o[j] = di * tanhf(h[j] * inv);
  }
  float* po = pout + (size_t)i * POUT;
#pragma unroll
  for (int j = 0; j < POUT; j += 4) *(float4*)(po + j) = make_float4(o[j], o[j+1], o[j+2], o[j+3]);
}

// ---------- final: gather(F_in=12) -> W3 -> l2norm -> Wc -> l2norm -> out ----------
__global__ void __launch_bounds__(BK) k_gather_final(
    const int* __restrict__ adj, const int* __restrict__ rowptr,
    const float* __restrict__ pin, const float* __restrict__ W3,
    const float* __restrict__ b3, const float* __restrict__ Wc,
    const float* __restrict__ bc, const float* __restrict__ dinv,
    float* __restrict__ out, int n) {
  constexpr int PIN = 16, FIN = 12, FOUT = 24, FC = 13;
  __shared__ float sW[FIN * FOUT];
  __shared__ float sb[FOUT];
  __shared__ float sWc[FOUT * FC];
  __shared__ float sbc[FC];
  for (int t = threadIdx.x; t < FIN * FOUT; t += BK) sW[t] = W3[t];
  for (int t = threadIdx.x; t < FOUT * FC; t += BK) sWc[t] = Wc[t];
  if (threadIdx.x < FOUT) sb[threadIdx.x] = b3[threadIdx.x];
  if (threadIdx.x < FC) sbc[threadIdx.x] = bc[threadIdx.x];
  __syncthreads();
  int i = blockIdx.x * blockDim.x + threadIdx.x;
  if (i >= n) return;
  float acc[PIN] = {};
  row_add<PIN>(pin + (size_t)i * PIN, acc);
  gather_acc<PIN>(adj, rowptr[i], rowptr[i + 1], pin, acc);
  float di = dinv[i];
  float h[FOUT];
  float ss = 0.f;
#pragma unroll
  for (int j = 0; j < FOUT; ++j) {
    float s = 0.f;
#pragma unroll
    for (int kk = 0; kk < FIN; ++kk) s = fmaf(acc[kk], sW[kk * FOUT + j], s);
    float t = fmaf(di, s, sb[j]);
    h[j] = t;
    ss += t * t;
  }
  float inv = 1.f / fmaxf(sqrtf(ss), 1e-12f);   // act3 = l2norm(h)
  float v[FC];
  float ss2 = 0.f;
#pragma unroll
  for (int j = 0; j < FC; ++j) {
    float s = sbc[j];
#pragma unroll
    for (int kk = 0; kk < FOUT; ++kk) s = fmaf(h[kk] * inv, sWc[kk * FC + j], s);
    v[j] = s;
    ss2 += s * s;
  }
  float inv2 = 1.f / fmaxf(sqrtf(ss2), 1e-12f);
#pragma unroll
  for (int j = 0; j < FC; ++j) out[(size_t)i * FC + j] = v[j] * inv2;
}

extern "C" void kernel_launch(void* const* d_in, const int* in_sizes, int n_in,
                              void* d_out, int out_size, void* d_ws, size_t ws_size,
                              hipStream_t stream) {
  const float* x  = (const float*)d_in[0];
  const int*   ei = (const int*)d_in[1];
  const float* W1 = (const float*)d_in[2];
  const float* b1 = (const float*)d_in[3];
  const float* W2 = (const float*)d_in[4];
  const float* b2 = (const float*)d_in[5];
  const float* W3 = (const float*)d_in[6];
  const float* b3 = (const float*)d_in[7];
  const float* Wc = (const float*)d_in[8];
  const float* bc = (const float*)d_in[9];
  float* out = (float*)d_out;

  const int n = NN;
  const int e = NE;
  const int* srcI = ei;       // row 0
  const int* dstI = ei + e;   // row 1

  // Workspace (words):
  //   dinv[N] | rowptr[N+8] | gtail[512] | sbase[512] | adj[E] | pad->64B | R
  // R hosts stg[NBA*CAPB] during build, then p1[4N] | p2[8N] | p3[16N].
  // p1 is 64B-aligned; 4N*4B and 8N*4B are multiples of 64 -> p2,p3 aligned.
  // Total ~56.0 MB (R8 proved >= 76 MB safe).
  float* ws = (float*)d_ws;
  float* dinv  = ws;
  int* rowptr  = (int*)(ws + n);            // N+8 (uses N+1, padded)
  int* gtail   = rowptr + n + 8;
  int* sbase   = gtail + 512;
  int* adj     = sbase + 512;
  size_t roff = (size_t)n + (n + 8) + 512 + 512 + e;
  roff = (roff + 15) & ~(size_t)15;         // round to 16 words = 64B
  float* R     = ws + roff;
  unsigned* stg = (unsigned*)R;
  float* p1 = R;                            // 4N  (64B-aligned)
  float* p2 = R + (size_t)4 * n;            // 8N  (64B-aligned)
  float* p3 = R + (size_t)12 * n;           // 16N (64B-aligned)

  const int gn = (n + BK - 1) / BK;

  // --- CSR build via binned counting sort, 2-D-hist-ordered scatter ---
  k_zero<<<2, BK, 0, stream>>>(gtail, 512);
  k_part<<<GPART, BKP, 0, stream>>>(srcI, dstI, stg, gtail, e);
  k_scan_sub<<<1, 512, 0, stream>>>(gtail, sbase);
  k_build<<<NBA, BK, 0, stream>>>(stg, gtail, sbase, rowptr, adj);
  k_dinv<<<gn, BK, 0, stream>>>(rowptr, dinv, n);

  // --- p1 = dinv * x ---
  k_prep<<<gn, BK, 0, stream>>>(x, dinv, p1, n);

  // --- Layer 1: gather p1 (16B rows) -> W1 -> tanh -> p2 = dinv*act ---
  k_gather_fused<4, 3, 6, 8, 0><<<gn, BK, 0, stream>>>(adj, rowptr, p1, W1, b1, dinv, p2, n);

  // --- Layer 2: gather p2 (32B rows) -> W2 -> l2norm+tanh -> p3 = dinv*act ---
  k_gather_fused<8, 6, 12, 16, 1><<<gn, BK, 0, stream>>>(adj, rowptr, p2, W2, b2, dinv, p3, n);

  // --- Layer 3 + classifier: gather p3 (64B rows) -> W3 -> l2norm -> Wc -> l2norm ---
  k_gather_final<<<gn, BK, 0, stream>>>(adj, rowptr, p3, W3, b3, Wc, bc, dinv, out, n);
}